// Round 9
// baseline (748.639 us; speedup 1.0000x reference)
//
#include <hip/hip_runtime.h>
#include <hip/hip_bf16.h>

#define BB 16384
#define KK 3
#define DD 1024
#define HH 16

typedef __attribute__((ext_vector_type(8))) short bf16x8;
typedef __attribute__((ext_vector_type(4))) float f32x4;
typedef unsigned int u32;

__device__ __forceinline__ void load_lds16(const void* g, void* l) {
  __builtin_amdgcn_global_load_lds(
      (const __attribute__((address_space(1))) u32*)g,
      (__attribute__((address_space(3))) u32*)l,
      16, 0, 0);
}

__device__ __forceinline__ unsigned short f2bf(float f) {
  __hip_bfloat16 h = __float2bfloat16(f);
  unsigned short u;
  __builtin_memcpy(&u, &h, 2);
  return u;
}

__device__ __forceinline__ float bf2f(unsigned short u) {
  union { float f; u32 i; } cv;
  cv.i = ((u32)u) << 16;
  return cv.f;
}

// ---------------------------------------------------------------- all weight casts in one launch
// 5 matrices x 1M elems. blocks 0-255: Wq, 256-511: Wk, 512-767: Wv,
// 768-1023: Wc, 1024-1279: Wo. Each block: 1024 float4s.
__global__ __launch_bounds__(256)
void cast_weights5(const float* __restrict__ Wq, const float* __restrict__ Wk,
                   const float* __restrict__ Wv, const float* __restrict__ Wc,
                   const float* __restrict__ Wo,
                   unsigned short* __restrict__ Wqkv,
                   unsigned short* __restrict__ Wcb,
                   unsigned short* __restrict__ Wob) {
  const int mat = blockIdx.x >> 8;
  const int inner = blockIdx.x & 255;
  const float* src = mat == 0 ? Wq : mat == 1 ? Wk : mat == 2 ? Wv
                   : mat == 3 ? Wc : Wo;
  unsigned short* dst = mat <= 2 ? Wqkv + (size_t)mat * DD * DD
                      : mat == 3 ? Wcb : Wob;
  const int base = inner * 1024 + threadIdx.x;
#pragma unroll
  for (int k = 0; k < 4; ++k) {
    const int i = base + k * 256;
    float4 v = ((const float4*)src)[i];
    ushort4 o;
    o.x = f2bf(v.x); o.y = f2bf(v.y); o.z = f2bf(v.z); o.w = f2bf(v.w);
    ((ushort4*)dst)[i] = o;
  }
}

// ---------------------------------------------------------------- fused GEMM: C = cast_bf16(A_f32) @ Bt^T + bias
// A: M x K fp32 (cast fused into staging). Bt: N x K bf16. Out: bf16.
// 256x256 tile, BK=32, 512 thr = 8 waves (2M x 4N), wave-tile 128x64.
// 2-slot LDS dbuf (2 x 32KB). Per tile: {vmcnt(0) [A-regs + B-LDS of kt landed]
// | cvt+2 ds_write_b128 (A kt, swizzled dest) | lgkm0 | s_barrier | 12 ds_read
// | issue B-gload(kt+1) + 4 A-dwordx4(kt+1) | 32 MFMA (compiler counted-lgkm)}.
// One barrier/tile (R7-structure, QKV measured 336us/41% MfmaUtil).
// WAR safety: writes to slot (kt+1)&1 issue after barrier(kt); all waves
// passed barrier(kt) => their reads of slot (kt-1)&1 were consumed by MFMAs.
// Numerics: __float2bfloat16 (RNE) == old cast kernel => absmax unchanged.
__global__ __launch_bounds__(512, 2)
void gemm_f32a(const float* __restrict__ A,
               const __hip_bfloat16* __restrict__ Bt,
               const float* __restrict__ bias,
               unsigned short* __restrict__ Cout,
               int M, int N, int K) {
  __shared__ __align__(128) char lds[65536];

  const int nTn = N >> 8;
  const int nwg = (M >> 8) * nTn;
  int bid = blockIdx.x;
  bid = (bid & 7) * (nwg >> 3) + (bid >> 3);  // bijective XCD swizzle (nwg%8==0)
  const int tm = bid / nTn;
  const int tn = bid % nTn;

  const int tid = threadIdx.x;
  const int l = tid & 63;
  const int w = tid >> 6;
  const int wm = w >> 2;   // 0..1
  const int wn = w & 3;    // 0..3
  const int l15 = l & 15;
  const int g = l >> 4;
  const int l7 = l15 & 7;

  // fragment-read byte offsets inside a 32KB slot (R3-verified, conflicts=0)
  const int aBase = (l15 << 7) + (((wm << 2) + g) ^ l7) * 16;
  const int bBase = 16384 + ((((wn & 1) << 6) + l15) << 7) +
                    ((((wn >> 1) << 2) + g) ^ l7) * 16;

  // ---- A reg-staging geometry (fp32 source; swizzled ds_write dest)
  const int qa = tid & 7;                       // logical chunk
  const int r1 = ((qa >> 2) << 7) + (tid >> 3); // rows {0-63, 128-191}
  const float* As = A + ((size_t)(tm * 256 + r1)) * K + ((qa & 3) << 3);
  const int da = ((r1 & 127) << 7) + ((qa ^ (r1 & 7)) << 4);  // phys dest

  // ---- B staging geometry (bf16 gload_lds; pre-swizzled source)
  const size_t strideB = (size_t)K * 2;
  const char* Bb = (const char*)Bt + (size_t)tn * 256 * strideB;
  const int qb = (tid & 7) ^ ((tid >> 3) & 7);
  const size_t gb0 = (size_t)((qb >> 2) * 128 + (tid >> 3)) * strideB +
                     (size_t)((qb & 3) << 4);
  const size_t gb1 = gb0 + (size_t)64 * strideB;
  const int sld = tid << 4;

  f32x4 acc[8][4] = {};
  float a0[8], a1[8];
  const int nkt = K >> 5;  // BK = 32

#define LOAD_A(T)                                                         \
  {                                                                       \
    const float* s = As + ((T) << 5);                                     \
    *(float4*)&a0[0] = *(const float4*)(s);                               \
    *(float4*)&a0[4] = *(const float4*)(s + 4);                           \
    *(float4*)&a1[0] = *(const float4*)(s + (size_t)64 * K);              \
    *(float4*)&a1[4] = *(const float4*)(s + (size_t)64 * K + 4);          \
  }
#define LOAD_B(T)                                                         \
  {                                                                       \
    char* sb = lds + (((T) & 1) << 15);                                   \
    const char* gbp = Bb + ((size_t)(T) << 6);                            \
    load_lds16(gbp + gb0, sb + 16384 + sld);                              \
    load_lds16(gbp + gb1, sb + 24576 + sld);                              \
  }
#define WRITE_A(T)                                                        \
  {                                                                       \
    char* sb = lds + (((T) & 1) << 15);                                   \
    bf16x8 p0, p1;                                                        \
    _Pragma("unroll") for (int j = 0; j < 8; ++j) {                       \
      p0[j] = (short)f2bf(a0[j]);                                         \
      p1[j] = (short)f2bf(a1[j]);                                         \
    }                                                                     \
    *(bf16x8*)(sb + da) = p0;                                             \
    *(bf16x8*)(sb + 8192 + da) = p1;                                      \
  }

  LOAD_B(0);
  LOAD_A(0);

  for (int kt = 0; kt < nkt; ++kt) {
    asm volatile("s_waitcnt vmcnt(0)" ::: "memory");  // A-regs + B-LDS of kt
    WRITE_A(kt);
    asm volatile("s_waitcnt lgkmcnt(0)" ::: "memory");  // ds_writes visible
    __builtin_amdgcn_s_barrier();
    asm volatile("" ::: "memory");

    const char* slot = lds + ((kt & 1) << 15);
    bf16x8 bfr[4], af[8];
#pragma unroll
    for (int n = 0; n < 4; ++n)
      bfr[n] = *(const bf16x8*)(slot + bBase + (n << 11));
#pragma unroll
    for (int m = 0; m < 8; ++m)
      af[m] = *(const bf16x8*)(slot + aBase + (m << 11));

    if (kt + 1 < nkt) {
      LOAD_B(kt + 1);
      LOAD_A(kt + 1);
    }

    __builtin_amdgcn_s_setprio(1);
#pragma unroll
    for (int m = 0; m < 8; ++m)
#pragma unroll
      for (int n = 0; n < 4; ++n)
        acc[m][n] = __builtin_amdgcn_mfma_f32_16x16x32_bf16(af[m], bfr[n],
                                                            acc[m][n], 0, 0, 0);
    __builtin_amdgcn_s_setprio(0);
  }
#undef LOAD_A
#undef LOAD_B
#undef WRITE_A

  // epilogue: C/D layout col = lane&15, row = (lane>>4)*4 + reg  [m89-verified]
  const int cbase = tn * 256 + (wn << 6) + l15;
  float b4[4];
#pragma unroll
  for (int n = 0; n < 4; ++n) b4[n] = bias[cbase + (n << 4)];
  const size_t rbase = (size_t)tm * 256 + (wm << 7) + ((l >> 4) << 2);
#pragma unroll
  for (int m = 0; m < 8; ++m) {
#pragma unroll
    for (int j = 0; j < 4; ++j) {
      const size_t row = rbase + (m << 4) + j;
#pragma unroll
      for (int n = 0; n < 4; ++n)
        Cout[row * N + cbase + (n << 4)] = f2bf(acc[m][n][j] + b4[n]);
    }
  }
}

// ---------------------------------------------------------------- GEMM (bf16 A): out-projection
// R8 8-phase kernel, unchanged (only <true> instantiated now).
template <bool OUT_F32>
__global__ __launch_bounds__(512, 2)
void gemm256(const __hip_bfloat16* __restrict__ A,
             const __hip_bfloat16* __restrict__ Bt,
             const float* __restrict__ bias,
             void* __restrict__ Cout,
             int M, int N, int K) {
  __shared__ __align__(128) char lds[131072];

  const int nTn = N >> 8;
  const int nwg = (M >> 8) * nTn;
  int bid = blockIdx.x;
  bid = (bid & 7) * (nwg >> 3) + (bid >> 3);
  const int tm = bid / nTn;
  const int tn = bid % nTn;

  const int tid = threadIdx.x;
  const int l = tid & 63;
  const int w = tid >> 6;
  const int wm = w >> 2;
  const int wn = w & 3;
  const int l15 = l & 15;
  const int g = l >> 4;
  const int l7 = l15 & 7;

  const int cs0 = ((g ^ l7) << 4);
  const int cs1 = (((4 | g) ^ l7) << 4);
  const int aRowB = ((wm << 7) + l15) << 7;
  const int bColB = 32768 + (((wn << 6) + l15) << 7);

  const size_t strideK = (size_t)K * 2;
  const char* Ab = (const char*)A + (size_t)tm * 256 * strideK;
  const char* Bb = (const char*)Bt + (size_t)tn * 256 * strideK;
  const size_t sOff = (size_t)(tid >> 3) * strideK +
                      (size_t)(((tid & 7) ^ ((tid >> 3) & 7)) << 4);
  const int sldst = tid << 4;

  char* const sl0 = lds;
  char* const sl1 = lds + 65536;

  f32x4 acc[8][4] = {};
  bf16x8 aF[16], bF[8];
  const int njt = K >> 7;

#define STG_A(T, H)                                                        \
  {                                                                        \
    char* d = lds + (((T) & 1) << 16) + ((H) << 14) + sldst;               \
    const char* s = Ab + ((size_t)(T) << 7) +                              \
                    ((size_t)((H) << 7)) * strideK + sOff;                 \
    load_lds16(s, d);                                                      \
    load_lds16(s + 64 * strideK, d + 8192);                                \
  }
#define STG_B(T, H)                                                        \
  {                                                                        \
    char* d = lds + (((T) & 1) << 16) + 32768 + ((H) << 14) + sldst;       \
    const char* s = Bb + ((size_t)(T) << 7) +                              \
                    ((size_t)((H) << 7)) * strideK + sOff;                 \
    load_lds16(s, d);                                                      \
    load_lds16(s + 64 * strideK, d + 8192);                                \
  }
#define RD_A2(SB, m)                                                       \
  aF[2 * (m)] = *(const bf16x8*)((SB) + aRowB + ((m) << 11) + cs0);        \
  aF[2 * (m) + 1] = *(const bf16x8*)((SB) + aRowB + ((m) << 11) + cs1);
#define RD_B2(SB, n)                                                       \
  bF[2 * (n)] = *(const bf16x8*)((SB) + bColB + ((n) << 11) + cs0);        \
  bF[2 * (n) + 1] = *(const bf16x8*)((SB) + bColB + ((n) << 11) + cs1);
#define MFMA_Q(MH, NH)                                                     \
  __builtin_amdgcn_s_setprio(1);                                           \
  _Pragma("unroll") for (int mm = 0; mm < 4; ++mm)                         \
      _Pragma("unroll") for (int nn = 0; nn < 2; ++nn)                     \
          _Pragma("unroll") for (int kh = 0; kh < 2; ++kh)                 \
              acc[(MH)*4 + mm][(NH)*2 + nn] =                              \
                  __builtin_amdgcn_mfma_f32_16x16x32_bf16(                 \
                      aF[2 * ((MH)*4 + mm) + kh],                          \
                      bF[2 * ((NH)*2 + nn) + kh],                          \
                      acc[(MH)*4 + mm][(NH)*2 + nn], 0, 0, 0);             \
  __builtin_amdgcn_s_setprio(0);
#define BAR  __builtin_amdgcn_s_barrier(); asm volatile("" ::: "memory");
#define LGKM0 asm volatile("s_waitcnt lgkmcnt(0)" ::: "memory");

  STG_A(0, 0); STG_A(0, 1); STG_B(0, 0); STG_B(0, 1);
  STG_A(1, 0); STG_A(1, 1);
  asm volatile("s_waitcnt vmcnt(4)" ::: "memory");
  BAR

  for (int j = 0; j < njt; ++j) {
    const int t1 = 2 * j + 1, t2 = 2 * j + 2, t3 = 2 * j + 3;
    const bool full = (j < njt - 1);

    RD_B2(sl0, 0) RD_B2(sl0, 1)
    RD_A2(sl0, 0) RD_A2(sl0, 1) RD_A2(sl0, 2) RD_A2(sl0, 3)
    STG_B(t1, 0)
    BAR LGKM0 MFMA_Q(0, 0) BAR
    RD_A2(sl0, 4) RD_A2(sl0, 5) RD_A2(sl0, 6) RD_A2(sl0, 7)
    STG_B(t1, 1)
    BAR LGKM0 MFMA_Q(1, 0) BAR
    RD_B2(sl0, 2) RD_B2(sl0, 3)
    if (full) STG_A(t2, 0)
    BAR LGKM0 MFMA_Q(0, 1) BAR
    if (full) STG_A(t2, 1)
    if (full) { asm volatile("s_waitcnt vmcnt(4)" ::: "memory"); }
    else      { asm volatile("s_waitcnt vmcnt(0)" ::: "memory"); }
    BAR MFMA_Q(1, 1) BAR

    RD_B2(sl1, 0) RD_B2(sl1, 1)
    RD_A2(sl1, 0) RD_A2(sl1, 1) RD_A2(sl1, 2) RD_A2(sl1, 3)
    if (full) STG_B(t2, 0)
    BAR LGKM0 MFMA_Q(0, 0) BAR
    RD_A2(sl1, 4) RD_A2(sl1, 5) RD_A2(sl1, 6) RD_A2(sl1, 7)
    if (full) STG_B(t2, 1)
    BAR LGKM0 MFMA_Q(1, 0) BAR
    RD_B2(sl1, 2) RD_B2(sl1, 3)
    if (full) STG_A(t3, 0)
    BAR LGKM0 MFMA_Q(0, 1) BAR
    if (full) STG_A(t3, 1)
    if (full) { asm volatile("s_waitcnt vmcnt(4)" ::: "memory"); }
    else      { asm volatile("s_waitcnt vmcnt(0)" ::: "memory"); }
    BAR MFMA_Q(1, 1) BAR
  }
#undef STG_A
#undef STG_B
#undef RD_A2
#undef RD_B2
#undef MFMA_Q
#undef BAR
#undef LGKM0

  const int cbase = tn * 256 + (wn << 6) + l15;
  float b4[4];
#pragma unroll
  for (int n = 0; n < 4; ++n) b4[n] = bias[cbase + (n << 4)];
  const size_t rbase = (size_t)tm * 256 + (wm << 7) + ((l >> 4) << 2);
#pragma unroll
  for (int m = 0; m < 8; ++m) {
#pragma unroll
    for (int j = 0; j < 4; ++j) {
      const size_t row = rbase + (m << 4) + j;
#pragma unroll
      for (int n = 0; n < 4; ++n) {
        const int col = cbase + (n << 4);
        float v = acc[m][n][j] + b4[n];
        if (OUT_F32)
          ((float*)Cout)[row * N + col] = v;
        else
          ((unsigned short*)Cout)[row * N + col] = f2bf(v);
      }
    }
  }
}

// ---------------------------------------------------------------- attention
// 16 lanes per (b,h); lane x handles dims 4x..4x+3 via ushort4 (8B/lane loads).
__global__ __launch_bounds__(256)
void attn_kernel(const unsigned short* __restrict__ QKV,  // (B*3) x 3072
                 const unsigned short* __restrict__ Cp,   // B x 1024
                 unsigned short* __restrict__ Out) {      // (B*3) x 1024
  const int t = threadIdx.x;
  const int grp = (blockIdx.x << 4) + (t >> 4);
  const int x = t & 15;
  const int b = grp >> 4;   // H = 16
  const int h = grp & 15;

  const size_t col = (size_t)h * 64 + (x << 2);
  const size_t qbase = (size_t)b * 3 * 3072 + col;

  ushort4 cu = *(const ushort4*)&Cp[(size_t)b * 1024 + col];
  float c[4] = {bf2f(cu.x), bf2f(cu.y), bf2f(cu.z), bf2f(cu.w)};

  float q[3][4], kc[3][4], vc[3][4];
#pragma unroll
  for (int i = 0; i < 3; ++i) {
    ushort4 qu = *(const ushort4*)&QKV[qbase + (size_t)i * 3072];
    ushort4 ku = *(const ushort4*)&QKV[qbase + (size_t)i * 3072 + 1024];
    ushort4 vu = *(const ushort4*)&QKV[qbase + (size_t)i * 3072 + 2048];
    q[i][0] = bf2f(qu.x); q[i][1] = bf2f(qu.y); q[i][2] = bf2f(qu.z); q[i][3] = bf2f(qu.w);
    kc[i][0] = bf2f(ku.x) * c[0]; kc[i][1] = bf2f(ku.y) * c[1];
    kc[i][2] = bf2f(ku.z) * c[2]; kc[i][3] = bf2f(ku.w) * c[3];
    vc[i][0] = bf2f(vu.x) * c[0]; vc[i][1] = bf2f(vu.y) * c[1];
    vc[i][2] = bf2f(vu.z) * c[2]; vc[i][3] = bf2f(vu.w) * c[3];
  }

  float s[9];
#pragma unroll
  for (int i = 0; i < 3; ++i)
#pragma unroll
    for (int j = 0; j < 3; ++j)
      s[i * 3 + j] = q[i][0] * kc[j][0] + q[i][1] * kc[j][1] +
                     q[i][2] * kc[j][2] + q[i][3] * kc[j][3];

#pragma unroll
  for (int off = 8; off > 0; off >>= 1)
#pragma unroll
    for (int e = 0; e < 9; ++e)
      s[e] += __shfl_xor(s[e], off, 64);

  const float scale = 0.125f;  // 1/sqrt(64)
#pragma unroll
  for (int i = 0; i < 3; ++i) {
    float s0 = s[i * 3 + 0] * scale;
    float s1 = s[i * 3 + 1] * scale;
    float s2 = s[i * 3 + 2] * scale;
    float m = fmaxf(fmaxf(s0, s1), s2);
    float p0 = expf(s0 - m), p1 = expf(s1 - m), p2 = expf(s2 - m);
    float inv = 1.0f / (p0 + p1 + p2);
    ushort4 o;
    o.x = f2bf((p0 * vc[0][0] + p1 * vc[1][0] + p2 * vc[2][0]) * inv);
    o.y = f2bf((p0 * vc[0][1] + p1 * vc[1][1] + p2 * vc[2][1]) * inv);
    o.z = f2bf((p0 * vc[0][2] + p1 * vc[1][2] + p2 * vc[2][2]) * inv);
    o.w = f2bf((p0 * vc[0][3] + p1 * vc[1][3] + p2 * vc[2][3]) * inv);
    *(ushort4*)&Out[(size_t)(b * 3 + i) * 1024 + col] = o;
  }
}

// ---------------------------------------------------------------- launch
extern "C" void kernel_launch(void* const* d_in, const int* in_sizes, int n_in,
                              void* d_out, int out_size, void* d_ws, size_t ws_size,
                              hipStream_t stream) {
  const float* tokens = (const float*)d_in[0];
  const float* ctx    = (const float*)d_in[1];
  const float* Wq     = (const float*)d_in[2];
  const float* bq     = (const float*)d_in[3];
  const float* Wk     = (const float*)d_in[4];
  const float* bk     = (const float*)d_in[5];
  const float* Wv     = (const float*)d_in[6];
  const float* bv     = (const float*)d_in[7];
  const float* Wc     = (const float*)d_in[8];
  const float* bc     = (const float*)d_in[9];
  const float* Wo     = (const float*)d_in[10];
  const float* bo     = (const float*)d_in[11];

  const int M  = BB * KK;   // 49152 token rows
  const int Mc = BB;        // 16384 ctx rows
  const int D  = DD;        // 1024

  char* p = (char*)d_ws;
  auto carve = [&](size_t bytes) {
    char* r = p;
    p += (bytes + 255) & ~(size_t)255;
    return r;
  };
  unsigned short* AOut = (unsigned short*)carve((size_t)M * D * 2);      // attn out (bf16)
  unsigned short* Wqkv = (unsigned short*)carve((size_t)3 * D * D * 2);
  unsigned short* Wcb  = (unsigned short*)carve((size_t)D * D * 2);
  unsigned short* Wob  = (unsigned short*)carve((size_t)D * D * 2);
  float*          bqkv = (float*)carve((size_t)3 * D * 4);
  unsigned short* QKV  = (unsigned short*)carve((size_t)M * 3 * D * 2);
  unsigned short* Cpr  = (unsigned short*)carve((size_t)Mc * D * 2);

  // all weight casts in one launch
  hipLaunchKernelGGL(cast_weights5, dim3(1280), dim3(256), 0, stream,
                     Wq, Wk, Wv, Wc, Wo, Wqkv, Wcb, Wob);
  hipMemcpyAsync(bqkv, bq, D * 4, hipMemcpyDeviceToDevice, stream);
  hipMemcpyAsync(bqkv + D, bk, D * 4, hipMemcpyDeviceToDevice, stream);
  hipMemcpyAsync(bqkv + 2 * D, bv, D * 4, hipMemcpyDeviceToDevice, stream);

  // QKV projection with fused fp32->bf16 A-cast: 192*12 = 2304 blocks
  hipLaunchKernelGGL(gemm_f32a, dim3((M / 256) * (3 * D / 256)), dim3(512), 0, stream,
                     tokens, (const __hip_bfloat16*)Wqkv, bqkv, QKV, M, 3 * D, D);
  // ctx projection with fused A-cast: 64*4 = 256 blocks
  hipLaunchKernelGGL(gemm_f32a, dim3((Mc / 256) * (D / 256)), dim3(512), 0, stream,
                     ctx, (const __hip_bfloat16*)Wcb, bc, Cpr, Mc, D, D);
  // attention
  hipLaunchKernelGGL(attn_kernel, dim3(BB * HH / 16), dim3(256), 0, stream, QKV, Cpr, AOut);
  // output projection -> fp32 d_out with bias: 192*4 = 768 blocks
  hipLaunchKernelGGL((gemm256<true>), dim3((M / 256) * (D / 256)), dim3(512), 0, stream,
                     (const __hip_bfloat16*)AOut, (const __hip_bfloat16*)Wob, bo,
                     d_out, M, D, D);
}

// Round 10
// 678.364 us; speedup vs baseline: 1.1036x; 1.1036x over previous
//
#include <hip/hip_runtime.h>
#include <hip/hip_bf16.h>

#define BB 16384
#define KK 3
#define DD 1024
#define HH 16

typedef __attribute__((ext_vector_type(8))) short bf16x8;
typedef __attribute__((ext_vector_type(4))) float f32x4;
typedef unsigned int u32;

__device__ __forceinline__ void load_lds16(const void* g, void* l) {
  __builtin_amdgcn_global_load_lds(
      (const __attribute__((address_space(1))) u32*)g,
      (__attribute__((address_space(3))) u32*)l,
      16, 0, 0);
}

__device__ __forceinline__ unsigned short f2bf(float f) {
  __hip_bfloat16 h = __float2bfloat16(f);
  unsigned short u;
  __builtin_memcpy(&u, &h, 2);
  return u;
}

__device__ __forceinline__ float bf2f(unsigned short u) {
  union { float f; u32 i; } cv;
  cv.i = ((u32)u) << 16;
  return cv.f;
}

// ---------------------------------------------------------------- cast fp32 -> bf16
__global__ void cast_f32_bf16(const float* __restrict__ in,
                              unsigned short* __restrict__ out, int n4) {
  int stride = gridDim.x * blockDim.x;
  for (int i = blockIdx.x * blockDim.x + threadIdx.x; i < n4; i += stride) {
    float4 v = ((const float4*)in)[i];
    ushort4 o;
    o.x = f2bf(v.x);
    o.y = f2bf(v.y);
    o.z = f2bf(v.z);
    o.w = f2bf(v.w);
    ((ushort4*)out)[i] = o;
  }
}

// ---------------------------------------------------------------- all weight casts in one launch
__global__ __launch_bounds__(256)
void cast_weights5(const float* __restrict__ Wq, const float* __restrict__ Wk,
                   const float* __restrict__ Wv, const float* __restrict__ Wc,
                   const float* __restrict__ Wo,
                   unsigned short* __restrict__ Wqkv,
                   unsigned short* __restrict__ Wcb,
                   unsigned short* __restrict__ Wob) {
  const int mat = blockIdx.x >> 8;
  const int inner = blockIdx.x & 255;
  const float* src = mat == 0 ? Wq : mat == 1 ? Wk : mat == 2 ? Wv
                   : mat == 3 ? Wc : Wo;
  unsigned short* dst = mat <= 2 ? Wqkv + (size_t)mat * DD * DD
                      : mat == 3 ? Wcb : Wob;
  const int base = inner * 1024 + threadIdx.x;
#pragma unroll
  for (int k = 0; k < 4; ++k) {
    const int i = base + k * 256;
    float4 v = ((const float4*)src)[i];
    ushort4 o;
    o.x = f2bf(v.x); o.y = f2bf(v.y); o.z = f2bf(v.z); o.w = f2bf(v.w);
    ((ushort4*)dst)[i] = o;
  }
}

// ---------------------------------------------------------------- GEMM (bf16 A): R8 8-phase, proven 338us QKV / 41% MfmaUtil
template <bool OUT_F32>
__global__ __launch_bounds__(512, 2)
void gemm256(const __hip_bfloat16* __restrict__ A,
             const __hip_bfloat16* __restrict__ Bt,
             const float* __restrict__ bias,
             void* __restrict__ Cout,
             int M, int N, int K) {
  __shared__ __align__(128) char lds[131072];

  const int nTn = N >> 8;
  const int nwg = (M >> 8) * nTn;
  int bid = blockIdx.x;
  bid = (bid & 7) * (nwg >> 3) + (bid >> 3);
  const int tm = bid / nTn;
  const int tn = bid % nTn;

  const int tid = threadIdx.x;
  const int l = tid & 63;
  const int w = tid >> 6;
  const int wm = w >> 2;
  const int wn = w & 3;
  const int l15 = l & 15;
  const int g = l >> 4;
  const int l7 = l15 & 7;

  const int cs0 = ((g ^ l7) << 4);
  const int cs1 = (((4 | g) ^ l7) << 4);
  const int aRowB = ((wm << 7) + l15) << 7;
  const int bColB = 32768 + (((wn << 6) + l15) << 7);

  const size_t strideK = (size_t)K * 2;
  const char* Ab = (const char*)A + (size_t)tm * 256 * strideK;
  const char* Bb = (const char*)Bt + (size_t)tn * 256 * strideK;
  const size_t sOff = (size_t)(tid >> 3) * strideK +
                      (size_t)(((tid & 7) ^ ((tid >> 3) & 7)) << 4);
  const int sldst = tid << 4;

  char* const sl0 = lds;
  char* const sl1 = lds + 65536;

  f32x4 acc[8][4] = {};
  bf16x8 aF[16], bF[8];
  const int njt = K >> 7;

#define STG_A(T, H)                                                        \
  {                                                                        \
    char* d = lds + (((T) & 1) << 16) + ((H) << 14) + sldst;               \
    const char* s = Ab + ((size_t)(T) << 7) +                              \
                    ((size_t)((H) << 7)) * strideK + sOff;                 \
    load_lds16(s, d);                                                      \
    load_lds16(s + 64 * strideK, d + 8192);                                \
  }
#define STG_B(T, H)                                                        \
  {                                                                        \
    char* d = lds + (((T) & 1) << 16) + 32768 + ((H) << 14) + sldst;       \
    const char* s = Bb + ((size_t)(T) << 7) +                              \
                    ((size_t)((H) << 7)) * strideK + sOff;                 \
    load_lds16(s, d);                                                      \
    load_lds16(s + 64 * strideK, d + 8192);                                \
  }
#define RD_A2(SB, m)                                                       \
  aF[2 * (m)] = *(const bf16x8*)((SB) + aRowB + ((m) << 11) + cs0);        \
  aF[2 * (m) + 1] = *(const bf16x8*)((SB) + aRowB + ((m) << 11) + cs1);
#define RD_B2(SB, n)                                                       \
  bF[2 * (n)] = *(const bf16x8*)((SB) + bColB + ((n) << 11) + cs0);        \
  bF[2 * (n) + 1] = *(const bf16x8*)((SB) + bColB + ((n) << 11) + cs1);
#define MFMA_Q(MH, NH)                                                     \
  __builtin_amdgcn_s_setprio(1);                                           \
  _Pragma("unroll") for (int mm = 0; mm < 4; ++mm)                         \
      _Pragma("unroll") for (int nn = 0; nn < 2; ++nn)                     \
          _Pragma("unroll") for (int kh = 0; kh < 2; ++kh)                 \
              acc[(MH)*4 + mm][(NH)*2 + nn] =                              \
                  __builtin_amdgcn_mfma_f32_16x16x32_bf16(                 \
                      aF[2 * ((MH)*4 + mm) + kh],                          \
                      bF[2 * ((NH)*2 + nn) + kh],                          \
                      acc[(MH)*4 + mm][(NH)*2 + nn], 0, 0, 0);             \
  __builtin_amdgcn_s_setprio(0);
#define BAR  __builtin_amdgcn_s_barrier(); asm volatile("" ::: "memory");
#define LGKM0 asm volatile("s_waitcnt lgkmcnt(0)" ::: "memory");

  STG_A(0, 0); STG_A(0, 1); STG_B(0, 0); STG_B(0, 1);
  STG_A(1, 0); STG_A(1, 1);
  asm volatile("s_waitcnt vmcnt(4)" ::: "memory");
  BAR

  for (int j = 0; j < njt; ++j) {
    const int t1 = 2 * j + 1, t2 = 2 * j + 2, t3 = 2 * j + 3;
    const bool full = (j < njt - 1);

    RD_B2(sl0, 0) RD_B2(sl0, 1)
    RD_A2(sl0, 0) RD_A2(sl0, 1) RD_A2(sl0, 2) RD_A2(sl0, 3)
    STG_B(t1, 0)
    BAR LGKM0 MFMA_Q(0, 0) BAR
    RD_A2(sl0, 4) RD_A2(sl0, 5) RD_A2(sl0, 6) RD_A2(sl0, 7)
    STG_B(t1, 1)
    BAR LGKM0 MFMA_Q(1, 0) BAR
    RD_B2(sl0, 2) RD_B2(sl0, 3)
    if (full) STG_A(t2, 0)
    BAR LGKM0 MFMA_Q(0, 1) BAR
    if (full) STG_A(t2, 1)
    if (full) { asm volatile("s_waitcnt vmcnt(4)" ::: "memory"); }
    else      { asm volatile("s_waitcnt vmcnt(0)" ::: "memory"); }
    BAR MFMA_Q(1, 1) BAR

    RD_B2(sl1, 0) RD_B2(sl1, 1)
    RD_A2(sl1, 0) RD_A2(sl1, 1) RD_A2(sl1, 2) RD_A2(sl1, 3)
    if (full) STG_B(t2, 0)
    BAR LGKM0 MFMA_Q(0, 0) BAR
    RD_A2(sl1, 4) RD_A2(sl1, 5) RD_A2(sl1, 6) RD_A2(sl1, 7)
    if (full) STG_B(t2, 1)
    BAR LGKM0 MFMA_Q(1, 0) BAR
    RD_B2(sl1, 2) RD_B2(sl1, 3)
    if (full) STG_A(t3, 0)
    BAR LGKM0 MFMA_Q(0, 1) BAR
    if (full) STG_A(t3, 1)
    if (full) { asm volatile("s_waitcnt vmcnt(4)" ::: "memory"); }
    else      { asm volatile("s_waitcnt vmcnt(0)" ::: "memory"); }
    BAR MFMA_Q(1, 1) BAR
  }
#undef STG_A
#undef STG_B
#undef RD_A2
#undef RD_B2
#undef MFMA_Q
#undef BAR
#undef LGKM0

  const int cbase = tn * 256 + (wn << 6) + l15;
  float b4[4];
#pragma unroll
  for (int n = 0; n < 4; ++n) b4[n] = bias[cbase + (n << 4)];
  const size_t rbase = (size_t)tm * 256 + (wm << 7) + ((l >> 4) << 2);
#pragma unroll
  for (int m = 0; m < 8; ++m) {
#pragma unroll
    for (int j = 0; j < 4; ++j) {
      const size_t row = rbase + (m << 4) + j;
#pragma unroll
      for (int n = 0; n < 4; ++n) {
        const int col = cbase + (n << 4);
        float v = acc[m][n][j] + b4[n];
        if (OUT_F32)
          ((float*)Cout)[row * N + col] = v;
        else
          ((unsigned short*)Cout)[row * N + col] = f2bf(v);
      }
    }
  }
}

// ---------------------------------------------------------------- CHALLENGER: fused-cast GEMM, depth-2 pipeline
// C = cast_bf16(A_f32) @ Bt^T + bias, bf16 out. 256x256, BK=32, 8 waves.
// LDS 80KB: A 2 slots x 16KB @0 (parity kt&1), B 3 slots x 16KB @32768 (kt%3).
// A staged via regs (2 named sets, alternated by 2x unroll): 4 dwordx4/tile.
// B via 2 gload_lds/tile. Loads issued 2 TILES AHEAD; steady wait vmcnt(6)
// (= the 6 loads of kt+1 outstanding), vmcnt(0) only at the last tile.
// Per tile: {vmcnt(6) | cvt+2 ds_write (A kt) | lgkm0 | barrier | 12 ds_read |
//            issue A(kt+2)->regs + B(kt+2)->slot | 32 MFMA (counted lgkm)}.
// WAR safety: A slot (kt&1) written between barrier(kt-?)... every region's
// previous readers drained by the lgkm0+barrier one tile before its rewrite
// (A: distance-2 parity; B: distance-3 ring) -- all issues occur after that
// barrier, so the VMEM/LDS writes cannot beat the drained reads.
__global__ __launch_bounds__(512, 2)
void gemm_qkvF(const float* __restrict__ A,
               const __hip_bfloat16* __restrict__ Bt,
               const float* __restrict__ bias,
               unsigned short* __restrict__ Cout,
               int M, int N, int K) {
  __shared__ __align__(128) char lds[81920];

  const int nTn = N >> 8;
  const int nwg = (M >> 8) * nTn;
  int bid = blockIdx.x;
  bid = (bid & 7) * (nwg >> 3) + (bid >> 3);
  const int tm = bid / nTn;
  const int tn = bid % nTn;

  const int tid = threadIdx.x;
  const int l = tid & 63;
  const int w = tid >> 6;
  const int wm = w >> 2;
  const int wn = w & 3;
  const int l15 = l & 15;
  const int g = l >> 4;
  const int l7 = l15 & 7;

  // frag-read offsets (same verified swizzle; A sub-slot 16KB, B sub-slot 16KB)
  const int aBase = (l15 << 7) + (((wm << 2) + g) ^ l7) * 16;
  const int bBaseIn = ((((wn & 1) << 6) + l15) << 7) +
                      ((((wn >> 1) << 2) + g) ^ l7) * 16;

  // A reg-staging (fp32 source; swizzled ds_write dest)
  const int qa = tid & 7;
  const int r1 = ((qa >> 2) << 7) + (tid >> 3);  // rows {0-63, 128-191}
  const float* As = A + ((size_t)(tm * 256 + r1)) * K + ((qa & 3) << 3);
  const int da = ((r1 & 127) << 7) + ((qa ^ (r1 & 7)) << 4);

  // B staging (gload_lds; pre-swizzled source)
  const size_t strideB = (size_t)K * 2;
  const char* Bb = (const char*)Bt + (size_t)tn * 256 * strideB;
  const int qb = (tid & 7) ^ ((tid >> 3) & 7);
  const size_t gb0 = (size_t)((qb >> 2) * 128 + (tid >> 3)) * strideB +
                     (size_t)((qb & 3) << 4);
  const size_t gb1 = gb0 + (size_t)64 * strideB;
  const int sld = tid << 4;

  f32x4 acc[8][4] = {};
  float aX0[8], aX1[8], aY0[8], aY1[8];  // two named A reg sets (rule #20)
  const int nkt = K >> 5;
  int s = 0;  // B ring slot of current tile

#define LOAD_A(T, R0, R1)                                                 \
  {                                                                       \
    const float* sp = As + ((T) << 5);                                    \
    *(float4*)&R0[0] = *(const float4*)(sp);                              \
    *(float4*)&R0[4] = *(const float4*)(sp + 4);                          \
    *(float4*)&R1[0] = *(const float4*)(sp + (size_t)64 * K);             \
    *(float4*)&R1[4] = *(const float4*)(sp + (size_t)64 * K + 4);         \
  }
#define LOAD_B(T, S)                                                      \
  {                                                                       \
    char* sb = lds + 32768 + (S) * 16384;                                 \
    const char* gbp = Bb + ((size_t)(T) << 6);                            \
    load_lds16(gbp + gb0, sb + sld);                                      \
    load_lds16(gbp + gb1, sb + 8192 + sld);                               \
  }

#define TILE(KT, R0, R1)                                                  \
  {                                                                       \
    const int kt_ = (KT);                                                 \
    if (kt_ < nkt - 1)                                                    \
      asm volatile("s_waitcnt vmcnt(6)" ::: "memory");                    \
    else                                                                  \
      asm volatile("s_waitcnt vmcnt(0)" ::: "memory");                    \
    {                                                                     \
      char* sb = lds + ((kt_ & 1) << 14);                                 \
      bf16x8 p0, p1;                                                      \
      _Pragma("unroll") for (int j = 0; j < 8; ++j) {                     \
        p0[j] = (short)f2bf(R0[j]);                                       \
        p1[j] = (short)f2bf(R1[j]);                                       \
      }                                                                   \
      *(bf16x8*)(sb + da) = p0;                                           \
      *(bf16x8*)(sb + 8192 + da) = p1;                                    \
    }                                                                     \
    asm volatile("s_waitcnt lgkmcnt(0)" ::: "memory");                    \
    __builtin_amdgcn_s_barrier();                                         \
    asm volatile("" ::: "memory");                                        \
    const char* sA = lds + ((kt_ & 1) << 14);                             \
    const char* sB = lds + 32768 + s * 16384;                             \
    bf16x8 af[8], bfr[4];                                                 \
    _Pragma("unroll") for (int n = 0; n < 4; ++n)                         \
      bfr[n] = *(const bf16x8*)(sB + bBaseIn + (n << 11));                \
    _Pragma("unroll") for (int m = 0; m < 8; ++m)                         \
      af[m] = *(const bf16x8*)(sA + aBase + (m << 11));                   \
    if (kt_ + 2 < nkt) {                                                  \
      int s2 = s - 1; if (s2 < 0) s2 += 3;  /* (s+2)%3 */                 \
      LOAD_A(kt_ + 2, R0, R1);                                            \
      LOAD_B(kt_ + 2, s2);                                                \
    }                                                                     \
    __builtin_amdgcn_s_setprio(1);                                        \
    _Pragma("unroll") for (int m = 0; m < 8; ++m)                         \
      _Pragma("unroll") for (int n = 0; n < 4; ++n)                       \
        acc[m][n] = __builtin_amdgcn_mfma_f32_16x16x32_bf16(              \
            af[m], bfr[n], acc[m][n], 0, 0, 0);                           \
    __builtin_amdgcn_s_setprio(0);                                        \
    s = (s + 1 == 3) ? 0 : s + 1;                                         \
  }

  // prologue: tiles 0 and 1 in flight (12 loads)
  LOAD_A(0, aX0, aX1);
  LOAD_B(0, 0);
  LOAD_A(1, aY0, aY1);
  LOAD_B(1, 1);

  for (int kt = 0; kt < nkt; kt += 2) {
    TILE(kt, aX0, aX1)
    TILE(kt + 1, aY0, aY1)
  }
#undef TILE
#undef LOAD_A
#undef LOAD_B

  // epilogue (bf16 out)
  const int cbase = tn * 256 + (wn << 6) + l15;
  float b4[4];
#pragma unroll
  for (int n = 0; n < 4; ++n) b4[n] = bias[cbase + (n << 4)];
  const size_t rbase = (size_t)tm * 256 + (wm << 7) + ((l >> 4) << 2);
#pragma unroll
  for (int m = 0; m < 8; ++m) {
#pragma unroll
    for (int j = 0; j < 4; ++j) {
      const size_t row = rbase + (m << 4) + j;
#pragma unroll
      for (int n = 0; n < 4; ++n)
        Cout[row * N + cbase + (n << 4)] = f2bf(acc[m][n][j] + b4[n]);
    }
  }
}

// ---------------------------------------------------------------- attention
__global__ __launch_bounds__(256)
void attn_kernel(const unsigned short* __restrict__ QKV,  // (B*3) x 3072
                 const unsigned short* __restrict__ Cp,   // B x 1024
                 unsigned short* __restrict__ Out) {      // (B*3) x 1024
  const int t = threadIdx.x;
  const int grp = (blockIdx.x << 4) + (t >> 4);
  const int x = t & 15;
  const int b = grp >> 4;   // H = 16
  const int h = grp & 15;

  const size_t col = (size_t)h * 64 + (x << 2);
  const size_t qbase = (size_t)b * 3 * 3072 + col;

  ushort4 cu = *(const ushort4*)&Cp[(size_t)b * 1024 + col];
  float c[4] = {bf2f(cu.x), bf2f(cu.y), bf2f(cu.z), bf2f(cu.w)};

  float q[3][4], kc[3][4], vc[3][4];
#pragma unroll
  for (int i = 0; i < 3; ++i) {
    ushort4 qu = *(const ushort4*)&QKV[qbase + (size_t)i * 3072];
    ushort4 ku = *(const ushort4*)&QKV[qbase + (size_t)i * 3072 + 1024];
    ushort4 vu = *(const ushort4*)&QKV[qbase + (size_t)i * 3072 + 2048];
    q[i][0] = bf2f(qu.x); q[i][1] = bf2f(qu.y); q[i][2] = bf2f(qu.z); q[i][3] = bf2f(qu.w);
    kc[i][0] = bf2f(ku.x) * c[0]; kc[i][1] = bf2f(ku.y) * c[1];
    kc[i][2] = bf2f(ku.z) * c[2]; kc[i][3] = bf2f(ku.w) * c[3];
    vc[i][0] = bf2f(vu.x) * c[0]; vc[i][1] = bf2f(vu.y) * c[1];
    vc[i][2] = bf2f(vu.z) * c[2]; vc[i][3] = bf2f(vu.w) * c[3];
  }

  float s[9];
#pragma unroll
  for (int i = 0; i < 3; ++i)
#pragma unroll
    for (int j = 0; j < 3; ++j)
      s[i * 3 + j] = q[i][0] * kc[j][0] + q[i][1] * kc[j][1] +
                     q[i][2] * kc[j][2] + q[i][3] * kc[j][3];

#pragma unroll
  for (int off = 8; off > 0; off >>= 1)
#pragma unroll
    for (int e = 0; e < 9; ++e)
      s[e] += __shfl_xor(s[e], off, 64);

  const float scale = 0.125f;  // 1/sqrt(64)
#pragma unroll
  for (int i = 0; i < 3; ++i) {
    float s0 = s[i * 3 + 0] * scale;
    float s1 = s[i * 3 + 1] * scale;
    float s2 = s[i * 3 + 2] * scale;
    float m = fmaxf(fmaxf(s0, s1), s2);
    float p0 = expf(s0 - m), p1 = expf(s1 - m), p2 = expf(s2 - m);
    float inv = 1.0f / (p0 + p1 + p2);
    ushort4 o;
    o.x = f2bf((p0 * vc[0][0] + p1 * vc[1][0] + p2 * vc[2][0]) * inv);
    o.y = f2bf((p0 * vc[0][1] + p1 * vc[1][1] + p2 * vc[2][1]) * inv);
    o.z = f2bf((p0 * vc[0][2] + p1 * vc[1][2] + p2 * vc[2][2]) * inv);
    o.w = f2bf((p0 * vc[0][3] + p1 * vc[1][3] + p2 * vc[2][3]) * inv);
    *(ushort4*)&Out[(size_t)(b * 3 + i) * 1024 + col] = o;
  }
}

// ---------------------------------------------------------------- launch
extern "C" void kernel_launch(void* const* d_in, const int* in_sizes, int n_in,
                              void* d_out, int out_size, void* d_ws, size_t ws_size,
                              hipStream_t stream) {
  const float* tokens = (const float*)d_in[0];
  const float* ctx    = (const float*)d_in[1];
  const float* Wq     = (const float*)d_in[2];
  const float* bq     = (const float*)d_in[3];
  const float* Wk     = (const float*)d_in[4];
  const float* bk     = (const float*)d_in[5];
  const float* Wv     = (const float*)d_in[6];
  const float* bv     = (const float*)d_in[7];
  const float* Wc     = (const float*)d_in[8];
  const float* bc     = (const float*)d_in[9];
  const float* Wo     = (const float*)d_in[10];
  const float* bo     = (const float*)d_in[11];

  const int M  = BB * KK;   // 49152 token rows
  const int Mc = BB;        // 16384 ctx rows
  const int D  = DD;        // 1024
  const int Mh = M / 2;     // 24576 rows per A/B half

  char* p = (char*)d_ws;
  auto carve = [&](size_t bytes) {
    char* r = p;
    p += (bytes + 255) & ~(size_t)255;
    return r;
  };
  unsigned short* AOut = (unsigned short*)carve((size_t)M * D * 2);   // attn out
  unsigned short* Xh   = (unsigned short*)carve((size_t)Mh * D * 2);  // tokens bf16 (control half)
  unsigned short* Cin  = (unsigned short*)carve((size_t)Mc * D * 2);
  unsigned short* Wqkv = (unsigned short*)carve((size_t)3 * D * D * 2);
  unsigned short* Wcb  = (unsigned short*)carve((size_t)D * D * 2);
  unsigned short* Wob  = (unsigned short*)carve((size_t)D * D * 2);
  float*          bqkv = (float*)carve((size_t)3 * D * 4);
  unsigned short* QKV  = (unsigned short*)carve((size_t)M * 3 * D * 2);
  unsigned short* Cpr  = (unsigned short*)carve((size_t)Mc * D * 2);

  // casts
  hipLaunchKernelGGL(cast_f32_bf16, dim3(4096), dim3(256), 0, stream,
                     tokens, Xh, Mh * D / 4);
  hipLaunchKernelGGL(cast_f32_bf16, dim3(2048), dim3(256), 0, stream,
                     ctx, Cin, Mc * D / 4);
  hipLaunchKernelGGL(cast_weights5, dim3(1280), dim3(256), 0, stream,
                     Wq, Wk, Wv, Wc, Wo, Wqkv, Wcb, Wob);
  hipMemcpyAsync(bqkv, bq, D * 4, hipMemcpyDeviceToDevice, stream);
  hipMemcpyAsync(bqkv + D, bk, D * 4, hipMemcpyDeviceToDevice, stream);
  hipMemcpyAsync(bqkv + 2 * D, bv, D * 4, hipMemcpyDeviceToDevice, stream);

  // QKV projection A/B (disjoint row halves):
  //  CONTROL: cast half + proven gemm256       -> 96*12 = 1152 blocks
  //  CHALLENGER: fused-cast gemm_qkvF (depth-2) -> 1152 blocks
  hipLaunchKernelGGL((gemm256<false>), dim3((Mh / 256) * (3 * D / 256)), dim3(512), 0, stream,
                     (const __hip_bfloat16*)Xh, (const __hip_bfloat16*)Wqkv, bqkv,
                     (void*)QKV, Mh, 3 * D, D);
  hipLaunchKernelGGL(gemm_qkvF, dim3((Mh / 256) * (3 * D / 256)), dim3(512), 0, stream,
                     tokens + (size_t)Mh * D, (const __hip_bfloat16*)Wqkv, bqkv,
                     QKV + (size_t)Mh * 3 * D, Mh, 3 * D, D);

  // ctx projection: 64*4 = 256 blocks
  hipLaunchKernelGGL((gemm256<false>), dim3((Mc / 256) * (D / 256)), dim3(512), 0, stream,
                     (const __hip_bfloat16*)Cin, (const __hip_bfloat16*)Wcb, bc,
                     (void*)Cpr, Mc, D, D);
  // attention
  hipLaunchKernelGGL(attn_kernel, dim3(BB * HH / 16), dim3(256), 0, stream, QKV, Cpr, AOut);
  // output projection -> fp32 d_out with bias: 768 blocks
  hipLaunchKernelGGL((gemm256<true>), dim3((M / 256) * (D / 256)), dim3(512), 0, stream,
                     (const __hip_bfloat16*)AOut, (const __hip_bfloat16*)Wob, bo,
                     d_out, M, D, D);
}

// Round 11
// 642.411 us; speedup vs baseline: 1.1654x; 1.0560x over previous
//
#include <hip/hip_runtime.h>
#include <hip/hip_bf16.h>

#define BB 16384
#define KK 3
#define DD 1024
#define HH 16

typedef __attribute__((ext_vector_type(8))) short bf16x8;
typedef __attribute__((ext_vector_type(4))) float f32x4;
typedef unsigned int u32;

__device__ __forceinline__ void load_lds16(const void* g, void* l) {
  __builtin_amdgcn_global_load_lds(
      (const __attribute__((address_space(1))) u32*)g,
      (__attribute__((address_space(3))) u32*)l,
      16, 0, 0);
}

__device__ __forceinline__ unsigned short f2bf(float f) {
  __hip_bfloat16 h = __float2bfloat16(f);
  unsigned short u;
  __builtin_memcpy(&u, &h, 2);
  return u;
}

__device__ __forceinline__ float bf2f(unsigned short u) {
  union { float f; u32 i; } cv;
  cv.i = ((u32)u) << 16;
  return cv.f;
}

// ---------------------------------------------------------------- input casts (tokens + ctx) in ONE launch
__global__ __launch_bounds__(256)
void cast_inputs(const float* __restrict__ tokens, const float* __restrict__ ctx,
                 unsigned short* __restrict__ Xb, unsigned short* __restrict__ Cin) {
  const int nTok4 = BB * KK * DD / 4;           // 12,582,912
  const int nTot4 = nTok4 + BB * DD / 4;        // 16,777,216
  const int stride = gridDim.x * blockDim.x;
  for (int i = blockIdx.x * blockDim.x + threadIdx.x; i < nTot4; i += stride) {
    float4 v;
    if (i < nTok4) v = ((const float4*)tokens)[i];
    else           v = ((const float4*)ctx)[i - nTok4];
    ushort4 o;
    o.x = f2bf(v.x); o.y = f2bf(v.y); o.z = f2bf(v.z); o.w = f2bf(v.w);
    if (i < nTok4) ((ushort4*)Xb)[i] = o;
    else           ((ushort4*)Cin)[i - nTok4] = o;
  }
}

// ---------------------------------------------------------------- all weight casts in one launch
__global__ __launch_bounds__(256)
void cast_weights5(const float* __restrict__ Wq, const float* __restrict__ Wk,
                   const float* __restrict__ Wv, const float* __restrict__ Wc,
                   const float* __restrict__ Wo,
                   unsigned short* __restrict__ Wqkv,
                   unsigned short* __restrict__ Wcb,
                   unsigned short* __restrict__ Wob) {
  const int mat = blockIdx.x >> 8;
  const int inner = blockIdx.x & 255;
  const float* src = mat == 0 ? Wq : mat == 1 ? Wk : mat == 2 ? Wv
                   : mat == 3 ? Wc : Wo;
  unsigned short* dst = mat <= 2 ? Wqkv + (size_t)mat * DD * DD
                      : mat == 3 ? Wcb : Wob;
  const int base = inner * 1024 + threadIdx.x;
#pragma unroll
  for (int k = 0; k < 4; ++k) {
    const int i = base + k * 256;
    float4 v = ((const float4*)src)[i];
    ushort4 o;
    o.x = f2bf(v.x); o.y = f2bf(v.y); o.z = f2bf(v.z); o.w = f2bf(v.w);
    ((ushort4*)dst)[i] = o;
  }
}

// ---------------------------------------------------------------- shared GEMM body
// R7-proven structure (best measured: QKV 336us, MfmaUtil 41.5, conflicts 0):
// 256x256 tile, BK=32, 8 waves (2Mx4N), wave-tile 128x64; 4-slot LDS ring
// (4x32KB), stage t+3, vmcnt(8) steady (4/0 only in tail), ONE s_barrier per
// tile, NO lgkm drains (compiler emits counted lgkmcnt per MFMA operand).
// LDS layout per slot: A/B [128 lines][128B]; phys chunk = logical ^ (line&7)
// (pre-swizzled gload source, swizzled ds_read; dest linear).
// bias[col - biasOff] added in epilogue.
template <bool OUT_F32>
__device__ __forceinline__ void gemm_body(char* lds,
    const __hip_bfloat16* __restrict__ A, const __hip_bfloat16* __restrict__ Bt,
    const float* __restrict__ bias, int biasOff, void* __restrict__ Cout,
    int tm, int tn, int N, int K) {
  const int tid = threadIdx.x;
  const int l = tid & 63;
  const int w = tid >> 6;
  const int wm = w >> 2;   // 0..1
  const int wn = w & 3;    // 0..3
  const int l15 = l & 15;
  const int g = l >> 4;
  const int l7 = l15 & 7;

  const int aBase = (l15 << 7) + (((wm << 2) + g) ^ l7) * 16;
  const int bBase = 16384 + ((((wn & 1) << 6) + l15) << 7) +
                    ((((wn >> 1) << 2) + g) ^ l7) * 16;

  const size_t strideK = (size_t)K * 2;
  const char* Ab = (const char*)A + (size_t)tm * 256 * strideK;
  const char* Bb = (const char*)Bt + (size_t)tn * 256 * strideK;
  const int q = (tid & 7) ^ ((tid >> 3) & 7);
  const size_t g0 = (size_t)((q >> 2) * 128 + (tid >> 3)) * strideK + (q & 3) * 16;
  const size_t g1 = g0 + (size_t)64 * strideK;
  const int sld = tid << 4;

  f32x4 acc[8][4] = {};
  const int nkt = K >> 5;

#define STAGE_AB(T)                                                       \
  {                                                                       \
    char* sb = lds + (((T) & 3) << 15);                                   \
    const char* ga = Ab + ((size_t)(T) << 6);                             \
    const char* gb = Bb + ((size_t)(T) << 6);                             \
    load_lds16(ga + g0, sb + sld);                                        \
    load_lds16(ga + g1, sb + 8192 + sld);                                 \
    load_lds16(gb + g0, sb + 16384 + sld);                                \
    load_lds16(gb + g1, sb + 24576 + sld);                                \
  }

  STAGE_AB(0);
  STAGE_AB(1);
  STAGE_AB(2);

  for (int kt = 0; kt < nkt; ++kt) {
    if (kt <= nkt - 3)
      asm volatile("s_waitcnt vmcnt(8)" ::: "memory");
    else if (kt == nkt - 2)
      asm volatile("s_waitcnt vmcnt(4)" ::: "memory");
    else
      asm volatile("s_waitcnt vmcnt(0)" ::: "memory");
    __builtin_amdgcn_s_barrier();
    asm volatile("" ::: "memory");

    const char* slot = lds + ((kt & 3) << 15);
    bf16x8 bfr[4], af[8];
#pragma unroll
    for (int n = 0; n < 4; ++n)
      bfr[n] = *(const bf16x8*)(slot + bBase + (n << 11));
#pragma unroll
    for (int m = 0; m < 8; ++m)
      af[m] = *(const bf16x8*)(slot + aBase + (m << 11));

    if (kt + 3 < nkt) STAGE_AB(kt + 3);

    __builtin_amdgcn_s_setprio(1);
#pragma unroll
    for (int m = 0; m < 8; ++m)
#pragma unroll
      for (int n = 0; n < 4; ++n)
        acc[m][n] = __builtin_amdgcn_mfma_f32_16x16x32_bf16(af[m], bfr[n],
                                                            acc[m][n], 0, 0, 0);
    __builtin_amdgcn_s_setprio(0);
  }
#undef STAGE_AB

  // epilogue: C/D layout col = lane&15, row = (lane>>4)*4 + reg  [m89-verified]
  const int cbase = tn * 256 + (wn << 6) + l15;
  float b4[4];
#pragma unroll
  for (int n = 0; n < 4; ++n) b4[n] = bias[cbase + (n << 4) - biasOff];
  const size_t rbase = (size_t)tm * 256 + (wm << 7) + ((l >> 4) << 2);
#pragma unroll
  for (int m = 0; m < 8; ++m) {
#pragma unroll
    for (int j = 0; j < 4; ++j) {
      const size_t row = rbase + (m << 4) + j;
#pragma unroll
      for (int n = 0; n < 4; ++n) {
        const int col = cbase + (n << 4);
        float v = acc[m][n][j] + b4[n];
        if (OUT_F32)
          ((float*)Cout)[row * N + col] = v;
        else
          ((unsigned short*)Cout)[row * N + col] = f2bf(v);
      }
    }
  }
}

// ---------------------------------------------------------------- combined QKV + ctx GEMM (one dispatch)
// blocks 0..2303 (after swizzle): QKV tile; 2304..2559: ctx tile.
__global__ __launch_bounds__(512, 2)
void gemm_all(const __hip_bfloat16* __restrict__ Xq,
              const __hip_bfloat16* __restrict__ Wqkv,
              const float* __restrict__ bq, const float* __restrict__ bk,
              const float* __restrict__ bv,
              unsigned short* __restrict__ QKV,
              const __hip_bfloat16* __restrict__ Cin,
              const __hip_bfloat16* __restrict__ Wcb,
              const float* __restrict__ bc,
              unsigned short* __restrict__ Cpr) {
  __shared__ __align__(128) char lds[131072];
  const int nwgQ = (BB * KK / 256) * (3 * DD / 256);  // 2304
  const int nwg = nwgQ + (BB / 256) * (DD / 256);     // 2560
  int bid = blockIdx.x;
  bid = (bid & 7) * (nwg >> 3) + (bid >> 3);  // bijective XCD swizzle (2560%8==0)
  if (bid < nwgQ) {
    const int tm = bid / 12, tn = bid % 12;
    const int which = tn >> 2;  // 0:q 1:k 2:v (256-col tiles never straddle)
    const float* bp = which == 0 ? bq : which == 1 ? bk : bv;
    gemm_body<false>(lds, Xq, Wqkv, bp, which << 10, QKV, tm, tn, 3 * DD, DD);
  } else {
    const int b2 = bid - nwgQ;
    gemm_body<false>(lds, Cin, Wcb, bc, 0, Cpr, b2 / 4, b2 % 4, DD, DD);
  }
}

// ---------------------------------------------------------------- output projection -> fp32 d_out
__global__ __launch_bounds__(512, 2)
void gemm_out(const __hip_bfloat16* __restrict__ A,
              const __hip_bfloat16* __restrict__ Wob,
              const float* __restrict__ bo, float* __restrict__ C) {
  __shared__ __align__(128) char lds[131072];
  const int nwg = (BB * KK / 256) * (DD / 256);  // 768
  int bid = blockIdx.x;
  bid = (bid & 7) * (nwg >> 3) + (bid >> 3);
  gemm_body<true>(lds, A, Wob, bo, 0, C, bid / 4, bid % 4, DD, DD);
}

// ---------------------------------------------------------------- attention
// 16 lanes per (b,h); lane x handles dims 4x..4x+3 via ushort4 (8B/lane loads).
__global__ __launch_bounds__(256)
void attn_kernel(const unsigned short* __restrict__ QKV,  // (B*3) x 3072
                 const unsigned short* __restrict__ Cp,   // B x 1024
                 unsigned short* __restrict__ Out) {      // (B*3) x 1024
  const int t = threadIdx.x;
  const int grp = (blockIdx.x << 4) + (t >> 4);
  const int x = t & 15;
  const int b = grp >> 4;   // H = 16
  const int h = grp & 15;

  const size_t col = (size_t)h * 64 + (x << 2);
  const size_t qbase = (size_t)b * 3 * 3072 + col;

  ushort4 cu = *(const ushort4*)&Cp[(size_t)b * 1024 + col];
  float c[4] = {bf2f(cu.x), bf2f(cu.y), bf2f(cu.z), bf2f(cu.w)};

  float q[3][4], kc[3][4], vc[3][4];
#pragma unroll
  for (int i = 0; i < 3; ++i) {
    ushort4 qu = *(const ushort4*)&QKV[qbase + (size_t)i * 3072];
    ushort4 ku = *(const ushort4*)&QKV[qbase + (size_t)i * 3072 + 1024];
    ushort4 vu = *(const ushort4*)&QKV[qbase + (size_t)i * 3072 + 2048];
    q[i][0] = bf2f(qu.x); q[i][1] = bf2f(qu.y); q[i][2] = bf2f(qu.z); q[i][3] = bf2f(qu.w);
    kc[i][0] = bf2f(ku.x) * c[0]; kc[i][1] = bf2f(ku.y) * c[1];
    kc[i][2] = bf2f(ku.z) * c[2]; kc[i][3] = bf2f(ku.w) * c[3];
    vc[i][0] = bf2f(vu.x) * c[0]; vc[i][1] = bf2f(vu.y) * c[1];
    vc[i][2] = bf2f(vu.z) * c[2]; vc[i][3] = bf2f(vu.w) * c[3];
  }

  float s[9];
#pragma unroll
  for (int i = 0; i < 3; ++i)
#pragma unroll
    for (int j = 0; j < 3; ++j)
      s[i * 3 + j] = q[i][0] * kc[j][0] + q[i][1] * kc[j][1] +
                     q[i][2] * kc[j][2] + q[i][3] * kc[j][3];

#pragma unroll
  for (int off = 8; off > 0; off >>= 1)
#pragma unroll
    for (int e = 0; e < 9; ++e)
      s[e] += __shfl_xor(s[e], off, 64);

  const float scale = 0.125f;  // 1/sqrt(64)
#pragma unroll
  for (int i = 0; i < 3; ++i) {
    float s0 = s[i * 3 + 0] * scale;
    float s1 = s[i * 3 + 1] * scale;
    float s2 = s[i * 3 + 2] * scale;
    float m = fmaxf(fmaxf(s0, s1), s2);
    float p0 = expf(s0 - m), p1 = expf(s1 - m), p2 = expf(s2 - m);
    float inv = 1.0f / (p0 + p1 + p2);
    ushort4 o;
    o.x = f2bf((p0 * vc[0][0] + p1 * vc[1][0] + p2 * vc[2][0]) * inv);
    o.y = f2bf((p0 * vc[0][1] + p1 * vc[1][1] + p2 * vc[2][1]) * inv);
    o.z = f2bf((p0 * vc[0][2] + p1 * vc[1][2] + p2 * vc[2][2]) * inv);
    o.w = f2bf((p0 * vc[0][3] + p1 * vc[1][3] + p2 * vc[2][3]) * inv);
    *(ushort4*)&Out[(size_t)(b * 3 + i) * 1024 + col] = o;
  }
}

// ---------------------------------------------------------------- launch
extern "C" void kernel_launch(void* const* d_in, const int* in_sizes, int n_in,
                              void* d_out, int out_size, void* d_ws, size_t ws_size,
                              hipStream_t stream) {
  const float* tokens = (const float*)d_in[0];
  const float* ctx    = (const float*)d_in[1];
  const float* Wq     = (const float*)d_in[2];
  const float* bq     = (const float*)d_in[3];
  const float* Wk     = (const float*)d_in[4];
  const float* bk     = (const float*)d_in[5];
  const float* Wv     = (const float*)d_in[6];
  const float* bv     = (const float*)d_in[7];
  const float* Wc     = (const float*)d_in[8];
  const float* bc     = (const float*)d_in[9];
  const float* Wo     = (const float*)d_in[10];
  const float* bo     = (const float*)d_in[11];

  const int M  = BB * KK;   // 49152 token rows
  const int Mc = BB;        // 16384 ctx rows
  const int D  = DD;        // 1024

  char* p = (char*)d_ws;
  auto carve = [&](size_t bytes) {
    char* r = p;
    p += (bytes + 255) & ~(size_t)255;
    return r;
  };
  unsigned short* Xb   = (unsigned short*)carve((size_t)M * D * 2);   // tokens bf16; reused as attn out
  unsigned short* Cin  = (unsigned short*)carve((size_t)Mc * D * 2);
  unsigned short* Wqkv = (unsigned short*)carve((size_t)3 * D * D * 2);
  unsigned short* Wcb  = (unsigned short*)carve((size_t)D * D * 2);
  unsigned short* Wob  = (unsigned short*)carve((size_t)D * D * 2);
  unsigned short* QKV  = (unsigned short*)carve((size_t)M * 3 * D * 2);
  unsigned short* Cpr  = (unsigned short*)carve((size_t)Mc * D * 2);

  // 1) input casts (tokens + ctx), one launch
  hipLaunchKernelGGL(cast_inputs, dim3(4096), dim3(256), 0, stream,
                     tokens, ctx, Xb, Cin);
  // 2) weight casts, one launch
  hipLaunchKernelGGL(cast_weights5, dim3(1280), dim3(256), 0, stream,
                     Wq, Wk, Wv, Wc, Wo, Wqkv, Wcb, Wob);
  // 3) QKV + ctx projections, one dispatch (2560 blocks)
  hipLaunchKernelGGL(gemm_all, dim3(2560), dim3(512), 0, stream,
                     (const __hip_bfloat16*)Xb, (const __hip_bfloat16*)Wqkv,
                     bq, bk, bv, QKV,
                     (const __hip_bfloat16*)Cin, (const __hip_bfloat16*)Wcb,
                     bc, Cpr);
  // 4) attention (writes into Xb, dead after gemm_all)
  hipLaunchKernelGGL(attn_kernel, dim3(BB * HH / 16), dim3(256), 0, stream,
                     QKV, Cpr, Xb);
  // 5) output projection -> fp32 d_out with bias (768 blocks)
  hipLaunchKernelGGL(gemm_out, dim3(768), dim3(512), 0, stream,
                     (const __hip_bfloat16*)Xb, (const __hip_bfloat16*)Wob,
                     bo, (float*)d_out);
}

// Round 12
// 598.852 us; speedup vs baseline: 1.2501x; 1.0727x over previous
//
#include <hip/hip_runtime.h>
#include <hip/hip_bf16.h>

#define BB 16384
#define KK 3
#define DD 1024
#define HH 16

typedef __attribute__((ext_vector_type(8))) short bf16x8;
typedef __attribute__((ext_vector_type(4))) float f32x4;
typedef unsigned int u32;

__device__ __forceinline__ void load_lds16(const void* g, void* l) {
  __builtin_amdgcn_global_load_lds(
      (const __attribute__((address_space(1))) u32*)g,
      (__attribute__((address_space(3))) u32*)l,
      16, 0, 0);
}

__device__ __forceinline__ unsigned short f2bf(float f) {
  __hip_bfloat16 h = __float2bfloat16(f);
  unsigned short u;
  __builtin_memcpy(&u, &h, 2);
  return u;
}

__device__ __forceinline__ float bf2f(unsigned short u) {
  union { float f; u32 i; } cv;
  cv.i = ((u32)u) << 16;
  return cv.f;
}

// ---------------------------------------------------------------- input casts, branch-free block split
// blocks 0..3071: tokens (12.58M float4); blocks 3072..4095: ctx (4.19M float4)
__global__ __launch_bounds__(256)
void cast_inputs(const float* __restrict__ tokens, const float* __restrict__ ctx,
                 unsigned short* __restrict__ Xb, unsigned short* __restrict__ Cin) {
  const bool isCtx = blockIdx.x >= 3072;
  const float* src = isCtx ? ctx : tokens;
  unsigned short* dst = isCtx ? Cin : Xb;
  const int inner = isCtx ? (blockIdx.x - 3072) : blockIdx.x;
  const int base = inner * 4096 + threadIdx.x;
#pragma unroll
  for (int k = 0; k < 16; ++k) {
    const int i = base + k * 256;
    float4 v = ((const float4*)src)[i];
    ushort4 o;
    o.x = f2bf(v.x); o.y = f2bf(v.y); o.z = f2bf(v.z); o.w = f2bf(v.w);
    ((ushort4*)dst)[i] = o;
  }
}

// ---------------------------------------------------------------- all weight casts in one launch
__global__ __launch_bounds__(256)
void cast_weights5(const float* __restrict__ Wq, const float* __restrict__ Wk,
                   const float* __restrict__ Wv, const float* __restrict__ Wc,
                   const float* __restrict__ Wo,
                   unsigned short* __restrict__ Wqkv,
                   unsigned short* __restrict__ Wcb,
                   unsigned short* __restrict__ Wob) {
  const int mat = blockIdx.x >> 8;
  const int inner = blockIdx.x & 255;
  const float* src = mat == 0 ? Wq : mat == 1 ? Wk : mat == 2 ? Wv
                   : mat == 3 ? Wc : Wo;
  unsigned short* dst = mat <= 2 ? Wqkv + (size_t)mat * DD * DD
                      : mat == 3 ? Wcb : Wob;
  const int base = inner * 1024 + threadIdx.x;
#pragma unroll
  for (int k = 0; k < 4; ++k) {
    const int i = base + k * 256;
    float4 v = ((const float4*)src)[i];
    ushort4 o;
    o.x = f2bf(v.x); o.y = f2bf(v.y); o.z = f2bf(v.z); o.w = f2bf(v.w);
    ((ushort4*)dst)[i] = o;
  }
}

// ---------------------------------------------------------------- shared 8-phase GEMM body (R8-proven: QKV 338us / 41% MfmaUtil)
// 256x256 tile, BK=64, 8 waves (2Mx4N), wave-tile 128x64. LDS 128KB
// (2 buffers x (A 32KB + B 32KB)). Per 2-K-tile iteration, 8 phases:
//   {ds_read quadrant frags | stage 1 half-tile | [vmcnt(4) @P4/P8] | sbar |
//    lgkm0 | setprio1 16 MFMA setprio0 | sbar}
// Stages run 3-5 half-tiles ahead (P1/P2: t1-B, P3/P4: t2-A, P5/P6: t2-B,
// P7/P8: t3-A). Chunk-XOR swizzle phys = logical ^ (row&7), both-sides
// (pre-swizzled gload source + swizzled ds_read, linear dest): conflicts = 0.
template <bool OUT_F32>
__device__ __forceinline__ void gemm_body8(char* lds,
    const __hip_bfloat16* __restrict__ A, const __hip_bfloat16* __restrict__ Bt,
    const float* __restrict__ bias, int biasOff, void* __restrict__ Cout,
    int tm, int tn, int N, int K) {
  const int tid = threadIdx.x;
  const int l = tid & 63;
  const int w = tid >> 6;
  const int wm = w >> 2;
  const int wn = w & 3;
  const int l15 = l & 15;
  const int g = l >> 4;
  const int l7 = l15 & 7;

  const int cs0 = ((g ^ l7) << 4);
  const int cs1 = (((4 | g) ^ l7) << 4);
  const int aRowB = ((wm << 7) + l15) << 7;
  const int bColB = 32768 + (((wn << 6) + l15) << 7);

  const size_t strideK = (size_t)K * 2;
  const char* Ab = (const char*)A + (size_t)tm * 256 * strideK;
  const char* Bb = (const char*)Bt + (size_t)tn * 256 * strideK;
  const size_t sOff = (size_t)(tid >> 3) * strideK +
                      (size_t)(((tid & 7) ^ ((tid >> 3) & 7)) << 4);
  const int sldst = tid << 4;

  char* const sl0 = lds;
  char* const sl1 = lds + 65536;

  f32x4 acc[8][4] = {};
  bf16x8 aF[16], bF[8];
  const int njt = K >> 7;

#define STG_A(T, H)                                                        \
  {                                                                        \
    char* d = lds + (((T) & 1) << 16) + ((H) << 14) + sldst;               \
    const char* s = Ab + ((size_t)(T) << 7) +                              \
                    ((size_t)((H) << 7)) * strideK + sOff;                 \
    load_lds16(s, d);                                                      \
    load_lds16(s + 64 * strideK, d + 8192);                                \
  }
#define STG_B(T, H)                                                        \
  {                                                                        \
    char* d = lds + (((T) & 1) << 16) + 32768 + ((H) << 14) + sldst;       \
    const char* s = Bb + ((size_t)(T) << 7) +                              \
                    ((size_t)((H) << 7)) * strideK + sOff;                 \
    load_lds16(s, d);                                                      \
    load_lds16(s + 64 * strideK, d + 8192);                                \
  }
#define RD_A2(SB, m)                                                       \
  aF[2 * (m)] = *(const bf16x8*)((SB) + aRowB + ((m) << 11) + cs0);        \
  aF[2 * (m) + 1] = *(const bf16x8*)((SB) + aRowB + ((m) << 11) + cs1);
#define RD_B2(SB, n)                                                       \
  bF[2 * (n)] = *(const bf16x8*)((SB) + bColB + ((n) << 11) + cs0);        \
  bF[2 * (n) + 1] = *(const bf16x8*)((SB) + bColB + ((n) << 11) + cs1);
#define MFMA_Q(MH, NH)                                                     \
  __builtin_amdgcn_s_setprio(1);                                           \
  _Pragma("unroll") for (int mm = 0; mm < 4; ++mm)                         \
      _Pragma("unroll") for (int nn = 0; nn < 2; ++nn)                     \
          _Pragma("unroll") for (int kh = 0; kh < 2; ++kh)                 \
              acc[(MH)*4 + mm][(NH)*2 + nn] =                              \
                  __builtin_amdgcn_mfma_f32_16x16x32_bf16(                 \
                      aF[2 * ((MH)*4 + mm) + kh],                          \
                      bF[2 * ((NH)*2 + nn) + kh],                          \
                      acc[(MH)*4 + mm][(NH)*2 + nn], 0, 0, 0);             \
  __builtin_amdgcn_s_setprio(0);
#define BAR  __builtin_amdgcn_s_barrier(); asm volatile("" ::: "memory");
#define LGKM0 asm volatile("s_waitcnt lgkmcnt(0)" ::: "memory");

  STG_A(0, 0); STG_A(0, 1); STG_B(0, 0); STG_B(0, 1);
  STG_A(1, 0); STG_A(1, 1);
  asm volatile("s_waitcnt vmcnt(4)" ::: "memory");
  BAR

  for (int j = 0; j < njt; ++j) {
    const int t1 = 2 * j + 1, t2 = 2 * j + 2, t3 = 2 * j + 3;
    const bool full = (j < njt - 1);

    RD_B2(sl0, 0) RD_B2(sl0, 1)
    RD_A2(sl0, 0) RD_A2(sl0, 1) RD_A2(sl0, 2) RD_A2(sl0, 3)
    STG_B(t1, 0)
    BAR LGKM0 MFMA_Q(0, 0) BAR
    RD_A2(sl0, 4) RD_A2(sl0, 5) RD_A2(sl0, 6) RD_A2(sl0, 7)
    STG_B(t1, 1)
    BAR LGKM0 MFMA_Q(1, 0) BAR
    RD_B2(sl0, 2) RD_B2(sl0, 3)
    if (full) STG_A(t2, 0)
    BAR LGKM0 MFMA_Q(0, 1) BAR
    if (full) STG_A(t2, 1)
    if (full) { asm volatile("s_waitcnt vmcnt(4)" ::: "memory"); }
    else      { asm volatile("s_waitcnt vmcnt(0)" ::: "memory"); }
    BAR MFMA_Q(1, 1) BAR

    RD_B2(sl1, 0) RD_B2(sl1, 1)
    RD_A2(sl1, 0) RD_A2(sl1, 1) RD_A2(sl1, 2) RD_A2(sl1, 3)
    if (full) STG_B(t2, 0)
    BAR LGKM0 MFMA_Q(0, 0) BAR
    RD_A2(sl1, 4) RD_A2(sl1, 5) RD_A2(sl1, 6) RD_A2(sl1, 7)
    if (full) STG_B(t2, 1)
    BAR LGKM0 MFMA_Q(1, 0) BAR
    RD_B2(sl1, 2) RD_B2(sl1, 3)
    if (full) STG_A(t3, 0)
    BAR LGKM0 MFMA_Q(0, 1) BAR
    if (full) STG_A(t3, 1)
    if (full) { asm volatile("s_waitcnt vmcnt(4)" ::: "memory"); }
    else      { asm volatile("s_waitcnt vmcnt(0)" ::: "memory"); }
    BAR MFMA_Q(1, 1) BAR
  }
#undef STG_A
#undef STG_B
#undef RD_A2
#undef RD_B2
#undef MFMA_Q
#undef BAR
#undef LGKM0

  // epilogue: C/D layout col = lane&15, row = (lane>>4)*4 + reg  [m89-verified]
  const int cbase = tn * 256 + (wn << 6) + l15;
  float b4[4];
#pragma unroll
  for (int n = 0; n < 4; ++n) b4[n] = bias[cbase + (n << 4) - biasOff];
  const size_t rbase = (size_t)tm * 256 + (wm << 7) + ((l >> 4) << 2);
#pragma unroll
  for (int m = 0; m < 8; ++m) {
#pragma unroll
    for (int j = 0; j < 4; ++j) {
      const size_t row = rbase + (m << 4) + j;
#pragma unroll
      for (int n = 0; n < 4; ++n) {
        const int col = cbase + (n << 4);
        float v = acc[m][n][j] + b4[n];
        if (OUT_F32)
          ((float*)Cout)[row * N + col] = v;
        else
          ((unsigned short*)Cout)[row * N + col] = f2bf(v);
      }
    }
  }
}

// ---------------------------------------------------------------- QKV projection (bias selected per column range)
__global__ __launch_bounds__(512, 2)
void gemm_qkv(const __hip_bfloat16* __restrict__ Xb,
              const __hip_bfloat16* __restrict__ Wqkv,
              const float* __restrict__ bq, const float* __restrict__ bk,
              const float* __restrict__ bv,
              unsigned short* __restrict__ QKV) {
  __shared__ __align__(128) char lds[131072];
  const int nwg = (BB * KK / 256) * (3 * DD / 256);  // 2304
  int bid = blockIdx.x;
  bid = (bid & 7) * (nwg >> 3) + (bid >> 3);
  const int tm = bid / 12, tn = bid % 12;
  const int which = tn >> 2;  // 0:q 1:k 2:v
  const float* bp = which == 0 ? bq : which == 1 ? bk : bv;
  gemm_body8<false>(lds, Xb, Wqkv, bp, which << 10, QKV, tm, tn, 3 * DD, DD);
}

// ---------------------------------------------------------------- ctx projection
__global__ __launch_bounds__(512, 2)
void gemm_ctx(const __hip_bfloat16* __restrict__ Cin,
              const __hip_bfloat16* __restrict__ Wcb,
              const float* __restrict__ bc,
              unsigned short* __restrict__ Cpr) {
  __shared__ __align__(128) char lds[131072];
  const int nwg = (BB / 256) * (DD / 256);  // 256
  int bid = blockIdx.x;
  bid = (bid & 7) * (nwg >> 3) + (bid >> 3);
  gemm_body8<false>(lds, Cin, Wcb, bc, 0, Cpr, bid / 4, bid % 4, DD, DD);
}

// ---------------------------------------------------------------- output projection -> fp32 d_out
__global__ __launch_bounds__(512, 2)
void gemm_outp(const __hip_bfloat16* __restrict__ A,
               const __hip_bfloat16* __restrict__ Wob,
               const float* __restrict__ bo, float* __restrict__ C) {
  __shared__ __align__(128) char lds[131072];
  const int nwg = (BB * KK / 256) * (DD / 256);  // 768
  int bid = blockIdx.x;
  bid = (bid & 7) * (nwg >> 3) + (bid >> 3);
  gemm_body8<true>(lds, A, Wob, bo, 0, C, bid / 4, bid % 4, DD, DD);
}

// ---------------------------------------------------------------- attention
// 8 lanes per (b,h); lane x handles dims 8x..8x+7 via 16B loads (max
// vectorization). Head-dim reduce = 3 shfl_xor rounds within the 8-lane group.
__global__ __launch_bounds__(256)
void attn_kernel(const unsigned short* __restrict__ QKV,  // (B*3) x 3072
                 const unsigned short* __restrict__ Cp,   // B x 1024
                 unsigned short* __restrict__ Out) {      // (B*3) x 1024
  const int t = threadIdx.x;
  const int grp = (blockIdx.x << 5) + (t >> 3);  // 32 groups/block
  const int x = t & 7;
  const int b = grp >> 4;   // H = 16
  const int h = grp & 15;

  const size_t col = (size_t)h * 64 + (x << 3);
  const size_t qbase = (size_t)b * 3 * 3072 + col;

  bf16x8 cu = *(const bf16x8*)&Cp[(size_t)b * 1024 + col];
  float c[8];
#pragma unroll
  for (int d = 0; d < 8; ++d) c[d] = bf2f((unsigned short)cu[d]);

  float q[3][8], kc[3][8], vc[3][8];
#pragma unroll
  for (int i = 0; i < 3; ++i) {
    bf16x8 qu = *(const bf16x8*)&QKV[qbase + (size_t)i * 3072];
    bf16x8 ku = *(const bf16x8*)&QKV[qbase + (size_t)i * 3072 + 1024];
    bf16x8 vu = *(const bf16x8*)&QKV[qbase + (size_t)i * 3072 + 2048];
#pragma unroll
    for (int d = 0; d < 8; ++d) {
      q[i][d] = bf2f((unsigned short)qu[d]);
      kc[i][d] = bf2f((unsigned short)ku[d]) * c[d];
      vc[i][d] = bf2f((unsigned short)vu[d]) * c[d];
    }
  }

  float s[9];
#pragma unroll
  for (int i = 0; i < 3; ++i)
#pragma unroll
    for (int j = 0; j < 3; ++j) {
      float acc = 0.f;
#pragma unroll
      for (int d = 0; d < 8; ++d) acc += q[i][d] * kc[j][d];
      s[i * 3 + j] = acc;
    }

  // reduce across the 8-lane group (head dim)
#pragma unroll
  for (int off = 4; off > 0; off >>= 1)
#pragma unroll
    for (int e = 0; e < 9; ++e)
      s[e] += __shfl_xor(s[e], off, 64);

  const float scale = 0.125f;  // 1/sqrt(64)
#pragma unroll
  for (int i = 0; i < 3; ++i) {
    float s0 = s[i * 3 + 0] * scale;
    float s1 = s[i * 3 + 1] * scale;
    float s2 = s[i * 3 + 2] * scale;
    float m = fmaxf(fmaxf(s0, s1), s2);
    float p0 = expf(s0 - m), p1 = expf(s1 - m), p2 = expf(s2 - m);
    float inv = 1.0f / (p0 + p1 + p2);
    bf16x8 o;
#pragma unroll
    for (int d = 0; d < 8; ++d)
      o[d] = (short)f2bf((p0 * vc[0][d] + p1 * vc[1][d] + p2 * vc[2][d]) * inv);
    *(bf16x8*)&Out[(size_t)(b * 3 + i) * 1024 + col] = o;
  }
}

// ---------------------------------------------------------------- launch
extern "C" void kernel_launch(void* const* d_in, const int* in_sizes, int n_in,
                              void* d_out, int out_size, void* d_ws, size_t ws_size,
                              hipStream_t stream) {
  const float* tokens = (const float*)d_in[0];
  const float* ctx    = (const float*)d_in[1];
  const float* Wq     = (const float*)d_in[2];
  const float* bq     = (const float*)d_in[3];
  const float* Wk     = (const float*)d_in[4];
  const float* bk     = (const float*)d_in[5];
  const float* Wv     = (const float*)d_in[6];
  const float* bv     = (const float*)d_in[7];
  const float* Wc     = (const float*)d_in[8];
  const float* bc     = (const float*)d_in[9];
  const float* Wo     = (const float*)d_in[10];
  const float* bo     = (const float*)d_in[11];

  const int M  = BB * KK;   // 49152 token rows
  const int Mc = BB;        // 16384 ctx rows
  const int D  = DD;        // 1024

  char* p = (char*)d_ws;
  auto carve = [&](size_t bytes) {
    char* r = p;
    p += (bytes + 255) & ~(size_t)255;
    return r;
  };
  unsigned short* Xb   = (unsigned short*)carve((size_t)M * D * 2);   // tokens bf16; reused as attn out
  unsigned short* Cin  = (unsigned short*)carve((size_t)Mc * D * 2);
  unsigned short* Wqkv = (unsigned short*)carve((size_t)3 * D * D * 2);
  unsigned short* Wcb  = (unsigned short*)carve((size_t)D * D * 2);
  unsigned short* Wob  = (unsigned short*)carve((size_t)D * D * 2);
  unsigned short* QKV  = (unsigned short*)carve((size_t)M * 3 * D * 2);
  unsigned short* Cpr  = (unsigned short*)carve((size_t)Mc * D * 2);

  // 1) input casts (tokens + ctx), one branch-free launch
  hipLaunchKernelGGL(cast_inputs, dim3(4096), dim3(256), 0, stream,
                     tokens, ctx, Xb, Cin);
  // 2) weight casts, one launch
  hipLaunchKernelGGL(cast_weights5, dim3(1280), dim3(256), 0, stream,
                     Wq, Wk, Wv, Wc, Wo, Wqkv, Wcb, Wob);
  // 3) QKV projection (2304 blocks)
  hipLaunchKernelGGL(gemm_qkv, dim3(2304), dim3(512), 0, stream,
                     (const __hip_bfloat16*)Xb, (const __hip_bfloat16*)Wqkv,
                     bq, bk, bv, QKV);
  // 4) ctx projection (256 blocks)
  hipLaunchKernelGGL(gemm_ctx, dim3(256), dim3(512), 0, stream,
                     (const __hip_bfloat16*)Cin, (const __hip_bfloat16*)Wcb,
                     bc, Cpr);
  // 5) attention (writes into Xb, dead after gemm_qkv)
  hipLaunchKernelGGL(attn_kernel, dim3(BB * HH / 32), dim3(256), 0, stream,
                     QKV, Cpr, Xb);
  // 6) output projection -> fp32 d_out with bias (768 blocks)
  hipLaunchKernelGGL(gemm_outp, dim3(768), dim3(512), 0, stream,
                     (const __hip_bfloat16*)Xb, (const __hip_bfloat16*)Wob,
                     bo, (float*)d_out);
}